// Round 1
// baseline (2797.322 us; speedup 1.0000x reference)
//
#include <hip/hip_runtime.h>
#include <hip/hip_bf16.h>

#define TB 2048
#define TT 256
#define HH 256
#define BC 8   // batches per block (M=16 MFMA tile half-padded)

typedef __attribute__((ext_vector_type(8))) short short8;
typedef __attribute__((ext_vector_type(4))) float floatx4;

__device__ __forceinline__ unsigned short f2bf(float f) {
    union { float f; unsigned u; } v; v.f = f;
    unsigned r = v.u + 0x7FFFu + ((v.u >> 16) & 1u);   // RNE, finite inputs only
    return (unsigned short)(r >> 16);
}
__device__ __forceinline__ float sigf(float x) {
    return __builtin_amdgcn_rcpf(1.f + __expf(-x));
}
__device__ __forceinline__ float tanh_(float x) {
    return 1.f - 2.f * __builtin_amdgcn_rcpf(__expf(2.f * x) + 1.f);
}

__global__ __launch_bounds__(1024) void lstm_fused(
    const float* __restrict__ y_hist, const float* __restrict__ h0,
    const float* __restrict__ c0, const float* __restrict__ W_ih,
    const float* __restrict__ W_hh, const float* __restrict__ b_ih,
    const float* __restrict__ b_hh, const float* __restrict__ W_fc,
    const float* __restrict__ b_fc, float* __restrict__ out)
{
    // hbuf: ping-pong h state, [batch 16][hidden 256] bf16, XOR-swizzled rows
    __shared__ __align__(16) unsigned short hbuf[2][16 * 256];
    __shared__ float xbuf[TT * 16];     // x transposed: [t][batch(16, padded)]
    __shared__ float outacc[32];

    const int tid = threadIdx.x;
    const int w  = tid >> 6;      // wave 0..15, owns hidden [16w, 16w+16)
    const int l  = tid & 63;
    const int lr = l & 15;        // batch lane (B/D col);  W-row lane (A row)
    const int lg = l >> 4;        // group 0..3
    const int b0 = blockIdx.x * BC;
    const int ubase = 16 * w + 4 * lg;   // hidden base for C/D rows of this lane

    // ---- stage x chunk (coalesced read, transposed store, zero-pad) ----
    for (int idx = tid; idx < TT * 16; idx += 1024) {
        int bb = idx >> 8, t = idx & 255;
        xbuf[t * 16 + bb] = (bb < BC) ? y_hist[(size_t)(b0 + bb) * TT + t] : 0.f;
    }
    // ---- stage h0 -> bf16 swizzled LDS (pad rows zero) ----
    {
        char* hb = (char*)&hbuf[0][0];
        for (int idx = tid; idx < 16 * 128; idx += 1024) {
            int bb = idx >> 7, d = idx & 127;   // d = dword = 2 hidden units
            unsigned val = 0;
            if (bb < BC) {
                const float* hp = &h0[(size_t)(b0 + bb) * HH + 2 * d];
                val = (unsigned)f2bf(hp[0]) | ((unsigned)f2bf(hp[1]) << 16);
            }
            *(unsigned*)(hb + bb * 512 + ((d * 4) ^ ((bb & 7) << 4))) = val;
        }
    }
    if (tid < 32) outacc[tid] = 0.f;

    // ---- per-lane constants ----
    float cc[4];
#pragma unroll
    for (int r = 0; r < 4; ++r)
        cc[r] = (lr < BC) ? c0[(size_t)(b0 + lr) * HH + ubase + r] : 0.f;

    float wxv[16], biasv[16], wfcv[8];
#pragma unroll
    for (int t4 = 0; t4 < 4; ++t4)
#pragma unroll
        for (int r = 0; r < 4; ++r) {
            int gc = t4 * 256 + ubase + r;
            wxv[t4 * 4 + r]   = W_ih[gc];
            biasv[t4 * 4 + r] = b_ih[gc] + b_hh[gc];
        }
#pragma unroll
    for (int o = 0; o < 2; ++o)
#pragma unroll
        for (int r = 0; r < 4; ++r)
            wfcv[o * 4 + r] = W_fc[o * HH + ubase + r];

    // ---- W_hh -> register-resident bf16 A-fragments ----
    // A-frag (tile t4, kstep s): lane holds W_hh[t4*256 + 16w + lr][8*lg + 32*s + 0..7]
    short8 wfrag[32];
    {
        const int wrow = 16 * w + lr;
        const int cb = 8 * lg;
#pragma unroll
        for (int t4 = 0; t4 < 4; ++t4)
#pragma unroll
            for (int s = 0; s < 8; ++s) {
                const float* p = &W_hh[(size_t)(t4 * 256 + wrow) * HH + cb + 32 * s];
                short8 f;
#pragma unroll
                for (int i = 0; i < 8; ++i) f[i] = (short)f2bf(p[i]);
                wfrag[t4 * 8 + s] = f;
            }
    }

    __syncthreads();

    const unsigned sw = (unsigned)((lr & 7) << 4);
    const unsigned rdbase = (unsigned)(lr * 512);
    float hv[4] = {0.f, 0.f, 0.f, 0.f};

    for (int t = 0; t < TT; ++t) {
        char* rb  = (char*)&hbuf[t & 1][0];
        char* wbp = (char*)&hbuf[(t + 1) & 1][0];

        // B-frags: h^T — lane holds h[batch lr][hidden 8*lg + 32*s + 0..7]
        short8 bf[8];
#pragma unroll
        for (int s = 0; s < 8; ++s)
            bf[s] = *(const short8*)(rb + rdbase + (((unsigned)(16 * lg + 64 * s)) ^ sw));

        float xv = xbuf[t * 16 + lr];
        floatx4 acc[4];
#pragma unroll
        for (int t4 = 0; t4 < 4; ++t4)
#pragma unroll
            for (int r = 0; r < 4; ++r)
                acc[t4][r] = fmaf(xv, wxv[t4 * 4 + r], biasv[t4 * 4 + r]);

#pragma unroll
        for (int s = 0; s < 8; ++s)
#pragma unroll
            for (int t4 = 0; t4 < 4; ++t4)
                acc[t4] = __builtin_amdgcn_mfma_f32_16x16x32_bf16(
                              wfrag[t4 * 8 + s], bf[s], acc[t4], 0, 0, 0);

        // gates -> c,h (lane: batch lr, hidden ubase+r)
#pragma unroll
        for (int r = 0; r < 4; ++r) {
            float iv = sigf(acc[0][r]);
            float fv = sigf(acc[1][r]);
            float gv = tanh_(acc[2][r]);
            float ov = sigf(acc[3][r]);
            float c2 = fmaf(fv, cc[r], iv * gv);
            cc[r] = c2;
            hv[r] = ov * tanh_(c2);
        }
        unsigned lo = (unsigned)f2bf(hv[0]) | ((unsigned)f2bf(hv[1]) << 16);
        unsigned hi = (unsigned)f2bf(hv[2]) | ((unsigned)f2bf(hv[3]) << 16);
        uint2 pk; pk.x = lo; pk.y = hi;
        *(uint2*)(wbp + rdbase + (((unsigned)(32 * w + 8 * lg)) ^ sw)) = pk;

        __syncthreads();
    }

    // ---- epilogue: out = h_T @ W_fc^T + b_fc (h_T from fp32 registers) ----
    float p0 = hv[0]*wfcv[0] + hv[1]*wfcv[1] + hv[2]*wfcv[2] + hv[3]*wfcv[3];
    float p1 = hv[0]*wfcv[4] + hv[1]*wfcv[5] + hv[2]*wfcv[6] + hv[3]*wfcv[7];
    p0 += __shfl_xor(p0, 16, 64); p0 += __shfl_xor(p0, 32, 64);
    p1 += __shfl_xor(p1, 16, 64); p1 += __shfl_xor(p1, 32, 64);
    if (lg == 0) {
        atomicAdd(&outacc[lr * 2 + 0], p0);
        atomicAdd(&outacc[lr * 2 + 1], p1);
    }
    __syncthreads();
    if (tid < BC * 2) {
        int bb = tid >> 1, o = tid & 1;
        out[(size_t)(b0 + bb) * 2 + o] = outacc[bb * 2 + o] + b_fc[o];
    }
}

extern "C" void kernel_launch(void* const* d_in, const int* in_sizes, int n_in,
                              void* d_out, int out_size, void* d_ws, size_t ws_size,
                              hipStream_t stream) {
    const float* y_hist = (const float*)d_in[0];
    const float* h0     = (const float*)d_in[1];
    const float* c0     = (const float*)d_in[2];
    const float* W_ih   = (const float*)d_in[3];
    const float* W_hh   = (const float*)d_in[4];
    const float* b_ih   = (const float*)d_in[5];
    const float* b_hh   = (const float*)d_in[6];
    const float* W_fc   = (const float*)d_in[7];
    const float* b_fc   = (const float*)d_in[8];

    lstm_fused<<<TB / BC, 1024, 0, stream>>>(
        y_hist, h0, c0, W_ih, W_hh, b_ih, b_hh, W_fc, b_fc, (float*)d_out);
}

// Round 2
// 2637.039 us; speedup vs baseline: 1.0608x; 1.0608x over previous
//
#include <hip/hip_runtime.h>
#include <hip/hip_bf16.h>

#define TB 2048
#define TT 256
#define HH 256
#define BC 8   // batches per block (M=16 MFMA tile half-padded)

typedef __attribute__((ext_vector_type(8))) short short8;
typedef __attribute__((ext_vector_type(4))) float floatx4;

__device__ __forceinline__ unsigned short f2bf(float f) {
    union { float f; unsigned u; } v; v.f = f;
    unsigned r = v.u + 0x7FFFu + ((v.u >> 16) & 1u);   // RNE, finite inputs only
    return (unsigned short)(r >> 16);
}
__device__ __forceinline__ float sigf(float x) {
    return __builtin_amdgcn_rcpf(1.f + __expf(-x));
}
__device__ __forceinline__ float tanh_(float x) {
    return 1.f - 2.f * __builtin_amdgcn_rcpf(__expf(2.f * x) + 1.f);
}

__global__ __attribute__((amdgpu_flat_work_group_size(1024, 1024),
                          amdgpu_waves_per_eu(4, 4)))
void lstm_fused(
    const float* __restrict__ y_hist, const float* __restrict__ h0,
    const float* __restrict__ c0, const float* __restrict__ W_ih,
    const float* __restrict__ W_hh, const float* __restrict__ b_ih,
    const float* __restrict__ b_hh, const float* __restrict__ W_fc,
    const float* __restrict__ b_fc, float* __restrict__ out)
{
    // hbuf: ping-pong h state, [batch 16][hidden 256] bf16, XOR-swizzled rows
    __shared__ __align__(16) unsigned short hbuf[2][16 * 256];
    __shared__ float xbuf[TT * 16];     // x transposed: [t][batch(16, padded)]
    __shared__ float outacc[32];

    const int tid = threadIdx.x;
    const int w  = tid >> 6;      // wave 0..15, owns hidden [16w, 16w+16)
    const int l  = tid & 63;
    const int lr = l & 15;        // batch lane (B/D col);  W-row lane (A row)
    const int lg = l >> 4;        // group 0..3
    const int b0 = blockIdx.x * BC;
    const int ubase = 16 * w + 4 * lg;   // hidden base for C/D rows of this lane

    // ---- stage x chunk (coalesced read, transposed store, zero-pad) ----
    for (int idx = tid; idx < TT * 16; idx += 1024) {
        int bb = idx >> 8, t = idx & 255;
        xbuf[t * 16 + bb] = (bb < BC) ? y_hist[(size_t)(b0 + bb) * TT + t] : 0.f;
    }
    // ---- stage h0 -> bf16 swizzled LDS (pad rows zero) ----
    {
        char* hb = (char*)&hbuf[0][0];
        for (int idx = tid; idx < 16 * 128; idx += 1024) {
            int bb = idx >> 7, d = idx & 127;   // d = dword = 2 hidden units
            unsigned val = 0;
            if (bb < BC) {
                const float* hp = &h0[(size_t)(b0 + bb) * HH + 2 * d];
                val = (unsigned)f2bf(hp[0]) | ((unsigned)f2bf(hp[1]) << 16);
            }
            *(unsigned*)(hb + bb * 512 + ((d * 4) ^ ((bb & 7) << 4))) = val;
        }
    }
    if (tid < 32) outacc[tid] = 0.f;

    // ---- per-lane constants ----
    float cc[4];
#pragma unroll
    for (int r = 0; r < 4; ++r)
        cc[r] = (lr < BC) ? c0[(size_t)(b0 + lr) * HH + ubase + r] : 0.f;

    float wxv[16], biasv[16], wfcv[8];
#pragma unroll
    for (int t4 = 0; t4 < 4; ++t4)
#pragma unroll
        for (int r = 0; r < 4; ++r) {
            int gc = t4 * 256 + ubase + r;
            wxv[t4 * 4 + r]   = W_ih[gc];
            biasv[t4 * 4 + r] = b_ih[gc] + b_hh[gc];
        }
#pragma unroll
    for (int o = 0; o < 2; ++o)
#pragma unroll
        for (int r = 0; r < 4; ++r)
            wfcv[o * 4 + r] = W_fc[o * HH + ubase + r];

    // ---- W_hh -> register-resident bf16 A-fragments ----
    // A-frag (tile t4, kstep s): lane holds W_hh[t4*256 + 16w + lr][8*lg + 32*s + 0..7]
    short8 wfrag[32];
    {
        const int wrow = 16 * w + lr;
        const int cb = 8 * lg;
#pragma unroll
        for (int t4 = 0; t4 < 4; ++t4)
#pragma unroll
            for (int s = 0; s < 8; ++s) {
                const float* p = &W_hh[(size_t)(t4 * 256 + wrow) * HH + cb + 32 * s];
                short8 f;
#pragma unroll
                for (int i = 0; i < 8; ++i) f[i] = (short)f2bf(p[i]);
                wfrag[t4 * 8 + s] = f;
            }
    }
    // Sever the link to the W_hh loads so the compiler can neither
    // rematerialize from global inside the t-loop nor sink the converts.
#pragma unroll
    for (int i = 0; i < 32; ++i)
        asm volatile("" : "+v"(wfrag[i]));

    __syncthreads();

    const unsigned sw = (unsigned)((lr & 7) << 4);
    const unsigned rdbase = (unsigned)(lr * 512);
    float hv[4] = {0.f, 0.f, 0.f, 0.f};

    for (int t = 0; t < TT; ++t) {
        char* rb  = (char*)&hbuf[t & 1][0];
        char* wbp = (char*)&hbuf[(t + 1) & 1][0];

        // B-frags: h^T — lane holds h[batch lr][hidden 8*lg + 32*s + 0..7]
        short8 bf[8];
#pragma unroll
        for (int s = 0; s < 8; ++s)
            bf[s] = *(const short8*)(rb + rdbase + (((unsigned)(16 * lg + 64 * s)) ^ sw));

        float xv = xbuf[t * 16 + lr];
        floatx4 acc[4];
#pragma unroll
        for (int t4 = 0; t4 < 4; ++t4)
#pragma unroll
            for (int r = 0; r < 4; ++r)
                acc[t4][r] = fmaf(xv, wxv[t4 * 4 + r], biasv[t4 * 4 + r]);

#pragma unroll
        for (int s = 0; s < 8; ++s)
#pragma unroll
            for (int t4 = 0; t4 < 4; ++t4)
                acc[t4] = __builtin_amdgcn_mfma_f32_16x16x32_bf16(
                              wfrag[t4 * 8 + s], bf[s], acc[t4], 0, 0, 0);

        // gates -> c,h (lane: batch lr, hidden ubase+r)
#pragma unroll
        for (int r = 0; r < 4; ++r) {
            float iv = sigf(acc[0][r]);
            float fv = sigf(acc[1][r]);
            float gv = tanh_(acc[2][r]);
            float ov = sigf(acc[3][r]);
            float c2 = fmaf(fv, cc[r], iv * gv);
            cc[r] = c2;
            hv[r] = ov * tanh_(c2);
        }
        unsigned lo = (unsigned)f2bf(hv[0]) | ((unsigned)f2bf(hv[1]) << 16);
        unsigned hi = (unsigned)f2bf(hv[2]) | ((unsigned)f2bf(hv[3]) << 16);
        uint2 pk; pk.x = lo; pk.y = hi;
        *(uint2*)(wbp + rdbase + (((unsigned)(32 * w + 8 * lg)) ^ sw)) = pk;

        __syncthreads();
    }

    // ---- epilogue: out = h_T @ W_fc^T + b_fc (h_T from fp32 registers) ----
    float p0 = hv[0]*wfcv[0] + hv[1]*wfcv[1] + hv[2]*wfcv[2] + hv[3]*wfcv[3];
    float p1 = hv[0]*wfcv[4] + hv[1]*wfcv[5] + hv[2]*wfcv[6] + hv[3]*wfcv[7];
    p0 += __shfl_xor(p0, 16, 64); p0 += __shfl_xor(p0, 32, 64);
    p1 += __shfl_xor(p1, 16, 64); p1 += __shfl_xor(p1, 32, 64);
    if (lg == 0) {
        atomicAdd(&outacc[lr * 2 + 0], p0);
        atomicAdd(&outacc[lr * 2 + 1], p1);
    }
    __syncthreads();
    if (tid < BC * 2) {
        int bb = tid >> 1, o = tid & 1;
        out[(size_t)(b0 + bb) * 2 + o] = outacc[bb * 2 + o] + b_fc[o];
    }
}

extern "C" void kernel_launch(void* const* d_in, const int* in_sizes, int n_in,
                              void* d_out, int out_size, void* d_ws, size_t ws_size,
                              hipStream_t stream) {
    const float* y_hist = (const float*)d_in[0];
    const float* h0     = (const float*)d_in[1];
    const float* c0     = (const float*)d_in[2];
    const float* W_ih   = (const float*)d_in[3];
    const float* W_hh   = (const float*)d_in[4];
    const float* b_ih   = (const float*)d_in[5];
    const float* b_hh   = (const float*)d_in[6];
    const float* W_fc   = (const float*)d_in[7];
    const float* b_fc   = (const float*)d_in[8];

    lstm_fused<<<TB / BC, 1024, 0, stream>>>(
        y_hist, h0, c0, W_ih, W_hh, b_ih, b_hh, W_fc, b_fc, (float*)d_out);
}

// Round 3
// 1953.772 us; speedup vs baseline: 1.4318x; 1.3497x over previous
//
#include <hip/hip_runtime.h>
#include <hip/hip_bf16.h>

// Team-of-2 LSTM: 256 blocks x 512 threads, block i pairs with i^128.
// Each block holds HALF of W_hh (512 gate rows x 256 K, bf16) register-
// resident: 128 VGPR/lane at 512 threads (cap 256 at waves_per_eu(2,2)).
// Per step the halves of h are exchanged through d_ws with agent-scope
// atomics + release/acquire flags (XCD-safe). Needs ws_size >= 2.1 MB.

#define TT 256
#define HH 256
#define BC 16

typedef __attribute__((ext_vector_type(8))) short short8;
typedef __attribute__((ext_vector_type(4))) float floatx4;
typedef unsigned long long ull;

__device__ __forceinline__ unsigned short f2bf(float f) {
    union { float f; unsigned u; } v; v.f = f;
    unsigned r = v.u + 0x7FFFu + ((v.u >> 16) & 1u);   // RNE, finite inputs only
    return (unsigned short)(r >> 16);
}
__device__ __forceinline__ float sigf(float x) {
    return __builtin_amdgcn_rcpf(1.f + __expf(-x));
}
__device__ __forceinline__ float tanh_(float x) {
    return 1.f - 2.f * __builtin_amdgcn_rcpf(__expf(2.f * x) + 1.f);
}

__global__ __attribute__((amdgpu_flat_work_group_size(512, 512),
                          amdgpu_waves_per_eu(2, 2)))
void lstm_team2(
    const float* __restrict__ y_hist, const float* __restrict__ h0,
    const float* __restrict__ c0, const float* __restrict__ W_ih,
    const float* __restrict__ W_hh, const float* __restrict__ b_ih,
    const float* __restrict__ b_hh, const float* __restrict__ W_fc,
    const float* __restrict__ b_fc, float* __restrict__ out,
    int* __restrict__ flags, char* __restrict__ hx)
{
    // h state: [batch 16][hidden 256] bf16, row stride 512B, XOR-swizzled
    __shared__ __align__(16) unsigned short hbuf[2][BC * 256];  // 16 KB
    __shared__ float xbuf[TT * BC];                             // 16 KB
    __shared__ float outacc[BC * 2];

    const int tid = threadIdx.x;
    const int w   = tid >> 6;          // wave 0..7
    const int l   = tid & 63;
    const int lr  = l & 15;            // batch lane (B col / C col)
    const int lg  = l >> 4;            // group 0..3
    const int bid = blockIdx.x;
    const int rho = bid >> 7;          // role 0/1: hidden half
    const int pid = bid ^ 128;         // partner block
    const int b0  = (bid & 127) * BC;  // team batch base
    const int hbase = rho * 128;       // this block's hidden half
    const int u   = hbase + 16 * w + 4 * lg;  // lane's hidden base (4 units)

    // ---- stage x: [t][batch] fp32 ----
    for (int idx = tid; idx < TT * BC; idx += 512) {
        int bb = idx >> 8, t = idx & 255;
        xbuf[t * BC + bb] = y_hist[(size_t)(b0 + bb) * TT + t];
    }
    // ---- stage h0 (full 256 hidden) -> bf16 swizzled LDS buf0 ----
    {
        char* hb = (char*)&hbuf[0][0];
        for (int idx = tid; idx < BC * 128; idx += 512) {
            int bb = idx >> 7, d = idx & 127;
            const float* hp = &h0[(size_t)(b0 + bb) * HH + 2 * d];
            unsigned val = (unsigned)f2bf(hp[0]) | ((unsigned)f2bf(hp[1]) << 16);
            *(unsigned*)(hb + bb * 512 + ((d * 4) ^ ((bb & 7) << 4))) = val;
        }
    }
    if (tid < BC * 2) outacc[tid] = 0.f;

    // ---- per-lane constants ----
    float cc[4];
#pragma unroll
    for (int r = 0; r < 4; ++r)
        cc[r] = c0[(size_t)(b0 + lr) * HH + u + r];

    float wxv[16], biasv[16];
#pragma unroll
    for (int g = 0; g < 4; ++g)
#pragma unroll
        for (int r = 0; r < 4; ++r) {
            int gc = g * 256 + u + r;
            wxv[g * 4 + r]   = W_ih[gc];
            biasv[g * 4 + r] = b_ih[gc] + b_hh[gc];
        }

    // ---- W half -> register-resident bf16 A-fragments (128 VGPR) ----
    short8 wfrag[32];
    {
        const int wrow = hbase + 16 * w + lr;
        const int cb = 8 * lg;
#pragma unroll
        for (int g = 0; g < 4; ++g)
#pragma unroll
            for (int s = 0; s < 8; ++s) {
                const float* p = &W_hh[(size_t)(g * 256 + wrow) * HH + cb + 32 * s];
                short8 f;
#pragma unroll
                for (int i = 0; i < 8; ++i) f[i] = (short)f2bf(p[i]);
                wfrag[g * 8 + s] = f;
            }
    }
#pragma unroll
    for (int i = 0; i < 32; ++i)
        asm volatile("" : "+v"(wfrag[i]));

    __syncthreads();

    const unsigned sw = (unsigned)((lr & 7) << 4);
    const unsigned rdbase = (unsigned)(lr * 512);
    const unsigned phbase2 = (unsigned)((1 - rho) * 256);  // partner half byte col
    const unsigned cw = (unsigned)(2 * u);                 // own half byte col
    float hv[4] = {0.f, 0.f, 0.f, 0.f};

#pragma unroll 2
    for (int t = 0; t < TT; ++t) {
        char* rb = (char*)&hbuf[t & 1][0];

        if (t > 0) {
            if (tid == 0) {
                while (__hip_atomic_load(flags + pid, __ATOMIC_ACQUIRE,
                                         __HIP_MEMORY_SCOPE_AGENT) < t)
                    __builtin_amdgcn_s_sleep(1);
            }
            __syncthreads();
            // stage partner half (4 KB) from LLC into LDS
            const ull* src = (const ull*)(hx + ((size_t)(pid * 2 + (t & 1))) * 4096);
            ull v = __hip_atomic_load(src + tid, __ATOMIC_RELAXED,
                                      __HIP_MEMORY_SCOPE_AGENT);
            int bb = tid >> 5;
            unsigned c = phbase2 + 8u * (tid & 31);
            *(ull*)(rb + bb * 512 + (c ^ ((unsigned)(bb & 7) << 4))) = v;
            __syncthreads();
        }

        // B-frags: h[batch lr][k = 8lg + 32s + 0..7]
        short8 bf[8];
#pragma unroll
        for (int s = 0; s < 8; ++s)
            bf[s] = *(const short8*)(rb + rdbase + (((unsigned)(16 * lg + 64 * s)) ^ sw));

        float xv = xbuf[t * BC + lr];
        floatx4 acc[4];
#pragma unroll
        for (int g = 0; g < 4; ++g)
#pragma unroll
            for (int r = 0; r < 4; ++r)
                acc[g][r] = fmaf(xv, wxv[g * 4 + r], biasv[g * 4 + r]);

#pragma unroll
        for (int s = 0; s < 8; ++s)
#pragma unroll
            for (int g = 0; g < 4; ++g)
                acc[g] = __builtin_amdgcn_mfma_f32_16x16x32_bf16(
                             wfrag[g * 8 + s], bf[s], acc[g], 0, 0, 0);

#pragma unroll
        for (int r = 0; r < 4; ++r) {
            float iv = sigf(acc[0][r]);
            float fv = sigf(acc[1][r]);
            float gv = tanh_(acc[2][r]);
            float ov = sigf(acc[3][r]);
            float c2 = fmaf(fv, cc[r], iv * gv);
            cc[r] = c2;
            hv[r] = ov * tanh_(c2);
        }
        unsigned lo = (unsigned)f2bf(hv[0]) | ((unsigned)f2bf(hv[1]) << 16);
        unsigned hi = (unsigned)f2bf(hv[2]) | ((unsigned)f2bf(hv[3]) << 16);
        ull pkv = (ull)lo | ((ull)hi << 32);

        // own half -> next LDS buffer
        char* wb = (char*)&hbuf[(t + 1) & 1][0];
        *(ull*)(wb + rdbase + (cw ^ sw)) = pkv;
        // own half -> partner via LLC (agent-scope store)
        ull* gdst = (ull*)(hx + ((size_t)(bid * 2 + ((t + 1) & 1))) * 4096
                              + lr * 256 + 32 * w + 8 * lg);
        __hip_atomic_store(gdst, pkv, __ATOMIC_RELAXED, __HIP_MEMORY_SCOPE_AGENT);

        __syncthreads();   // drains all waves' stores (vmcnt0) before flag
        if (tid == 0)
            __hip_atomic_store(flags + bid, t + 1, __ATOMIC_RELEASE,
                               __HIP_MEMORY_SCOPE_AGENT);
    }

    // ---- epilogue: partial out = h_T(half) @ W_fc^T, teams combine via atomics ----
    float wfcv[8];
#pragma unroll
    for (int o = 0; o < 2; ++o)
#pragma unroll
        for (int r = 0; r < 4; ++r)
            wfcv[o * 4 + r] = W_fc[o * HH + u + r];

    float p0 = hv[0]*wfcv[0] + hv[1]*wfcv[1] + hv[2]*wfcv[2] + hv[3]*wfcv[3];
    float p1 = hv[0]*wfcv[4] + hv[1]*wfcv[5] + hv[2]*wfcv[6] + hv[3]*wfcv[7];
    p0 += __shfl_xor(p0, 16, 64); p0 += __shfl_xor(p0, 32, 64);
    p1 += __shfl_xor(p1, 16, 64); p1 += __shfl_xor(p1, 32, 64);
    if (lg == 0) {
        atomicAdd(&outacc[lr * 2 + 0], p0);
        atomicAdd(&outacc[lr * 2 + 1], p1);
    }
    __syncthreads();
    if (tid < BC * 2) {
        int bb = tid >> 1, o = tid & 1;
        float v = outacc[tid] + (rho == 0 ? b_fc[o] : 0.f);
        atomicAdd(&out[(size_t)(b0 + bb) * 2 + o], v);
    }
}

extern "C" void kernel_launch(void* const* d_in, const int* in_sizes, int n_in,
                              void* d_out, int out_size, void* d_ws, size_t ws_size,
                              hipStream_t stream) {
    const float* y_hist = (const float*)d_in[0];
    const float* h0     = (const float*)d_in[1];
    const float* c0     = (const float*)d_in[2];
    const float* W_ih   = (const float*)d_in[3];
    const float* W_hh   = (const float*)d_in[4];
    const float* b_ih   = (const float*)d_in[5];
    const float* b_hh   = (const float*)d_in[6];
    const float* W_fc   = (const float*)d_in[7];
    const float* b_fc   = (const float*)d_in[8];

    int*  flags = (int*)d_ws;
    char* hx    = (char*)d_ws + 4096;   // 256 blocks x 2 parities x 4 KB = 2 MB

    // Reset flags every launch (graph-safe); zero out for atomicAdd epilogue.
    hipMemsetAsync(d_out, 0, (size_t)out_size * sizeof(float), stream);
    hipMemsetAsync(d_ws, 0, 4096, stream);

    lstm_team2<<<256, 512, 0, stream>>>(
        y_hist, h0, c0, W_ih, W_hh, b_ih, b_hh, W_fc, b_fc,
        (float*)d_out, flags, hx);
}